// Round 9
// baseline (100.450 us; speedup 1.0000x reference)
//
#include <hip/hip_runtime.h>
#include <math.h>
#include <stdint.h>

// SemiConv2d tropical conv: out = max_{ic,kh,kw} min(x_pad, K). f16-packed.
// R21: DELETE THE INTERMEDIATE. R20 post-mortem: LDS-staged scan (zero
// global gather) moved total only -1.5us => data-motion theory family
// dead (9 levers: loads/waves/bytes/pipeline/XCD/alignment/LDS all
// measured ~neutral). Budget: fill ~44 (harness re-poison, 76% HBM peak,
// irreducible) + setup ~5-6 + main ~25-30 + gaps. Last unfired lever:
// the xq PACK PASS itself (1274 blocks, ~5us, 5.2MB write + 31MB
// re-read) exists only to pre-convert f32->f16; the main kernel's
// staging loop does that inline for free (8 cvts/unit hidden under
// ds_write). K1 shrinks to 32-block table sort (~1-2us); main stages
// DIRECTLY from x (L3-resident 9.4MB) into the same LDS layout, borders
// at stage time. Same 2 launches; pack work + xq round-trip vanish;
// ws use drops to 61KB. Scan + f16 RTNE identical -> absmax 0.015625.
// Predict: 86.7 -> ~80-83. PRE-COMMIT: if >=85, every controllable
// component has resisted its matched lever; remaining = fill(44,
// HBM-roofline) + launch fixed + ~25us scan at an empirically hard
// floor -> declare ROOFLINE next round.

#define HH 96
#define WW 96
#define CIN 32
#define OCN 32
#define ROWB 208                                // 104 f16 per LDS row unit-stride
#define NROW 96                                 // sorted row-entries per oc
#define TBL_BYTES ((size_t)OCN * NROW * 16)
#define RMX_BYTES ((size_t)OCN * NROW * 4)
#define WS_NEED (TBL_BYTES + RMX_BYTES)
#define NEGH2 0xFC00FC00u
#define LDSU 2496                               // 32 ic * 6 rows * 13 units

typedef _Float16 h2 __attribute__((ext_vector_type(2)));
typedef uint32_t u4a4 __attribute__((ext_vector_type(4), aligned(4)));

__device__ __forceinline__ uint32_t pkmin_vs(uint32_t x, uint32_t k) {
    uint32_t d;
    asm("v_pk_min_f16 %0, %1, %2" : "=v"(d) : "v"(x), "s"(k));
    return d;
}
__device__ __forceinline__ uint32_t pkmin_vv(uint32_t a, uint32_t b) {
    uint32_t d;
    asm("v_pk_min_f16 %0, %1, %2" : "=v"(d) : "v"(a), "v"(b));
    return d;
}
__device__ __forceinline__ uint32_t pkmax(uint32_t a, uint32_t b) {
    uint32_t d;
    asm("v_pk_max_f16 %0, %1, %2" : "=v"(d) : "v"(a), "v"(b));
    return d;
}
__device__ __forceinline__ uint32_t packh2(float lo, float hi) {
    h2 p = {(_Float16)lo, (_Float16)hi};
    return __builtin_bit_cast(uint32_t, p);
}

// K1: per-oc row table sorted by rowmax desc. 32 blocks x 96 threads.
//   entry uint4 = {k0dup, k1dup, k2dup, LOCAL LDS byte off (ic*6+dh)*208}
//   rmx[rank]  = rowmax dup (exit threshold bounds all remaining k).
__global__ __launch_bounds__(96) void setup_tab(const float* __restrict__ kk,
                                                uint4* __restrict__ tbl,
                                                uint32_t* __restrict__ rmx) {
    __shared__ float rs[NROW];
    const int oc = blockIdx.x;
    const int t  = threadIdx.x;                 // 96 = ic*3 + dh
    const int ic = t / 3, dh = t - 3 * ic;
    const float* kp = kk + ((size_t)(oc * CIN + ic) * 3 + dh) * 3;
    float k0 = kp[0], k1 = kp[1], k2 = kp[2];
    float rm = fmaxf(fmaxf(k0, k1), k2);
    rs[t] = rm;
    __syncthreads();
    int rank = 0;
    for (int s = 0; s < NROW; ++s) {
        float v = rs[s];
        rank += (v > rm) || (v == rm && s < t);
    }
    uint32_t off = (uint32_t)(ic * 6 + dh) * ROWB;  // LOCAL offset in LDS tile
    tbl[oc * NROW + rank] = make_uint4(packh2(k0, k0), packh2(k1, k1),
                                       packh2(k2, k2), off);
    rmx[oc * NROW + rank] = packh2(rm, rm);
}

// Block = (n, 4 output h-rows, 8 ocs), 512 threads = 8 waves.
// Stage DIRECTLY from x: 6 padded rows (h = h0-1 .. h0+4) x 32 ic,
// f32 -> f16 inline, borders -> -inf. LDS row = 104 f16 covering
// w = -1..102 (unit j = px 8j-1..8j+6). Then each wave (one oc) scans
// its sorted rows from LDS with early exit. Lane = 6 px: wl 0..15
// (w0 = 6*wl), hr 0..3. Per row one 16B window at e.w + hr*208 + 12*wl
// gives d0..d3; pair q: kw0=d_q, kw1=align(d_{q+1},d_q), kw2=d_{q+1}.
__global__ __launch_bounds__(512, 4) void semiconv_x(const float* __restrict__ x,
                                                     const uint4* __restrict__ tbl,
                                                     const uint32_t* __restrict__ rmx,
                                                     float* __restrict__ out) {
    __shared__ uint4 lsd[LDSU];
    const int tid = threadIdx.x;
    const int b   = blockIdx.x;
    const int ocl = b & 3;
    const int t   = b >> 2;
    const int ht  = t % 24;
    const int n   = t / 24;
    const int h0  = ht * 4;

    // ---- stage 6 padded rows x 32 ic (2496 x 16B), f32->f16 inline ----
    const float* xn = x + (size_t)n * CIN * HH * WW;
#pragma unroll
    for (int i = 0; i < 5; ++i) {
        int u = tid + 512 * i;
        if (u < LDSU) {
            int ic = u / 78;                    // 6*13 units per ic
            int rr = u - ic * 78;
            int r  = rr / 13;
            int j  = rr - r * 13;
            int h  = h0 + r - 1;                // padded row hp = h0+r
            bool hv = (h >= 0) && (h < HH);
            const float* row = xn + ((size_t)ic * HH + (hv ? h : 0)) * WW;
            float v[8];
#pragma unroll
            for (int q = 0; q < 8; ++q) {
                int w = 8 * j - 1 + q;
                v[q] = (hv && w >= 0 && w < WW) ? row[w] : -INFINITY;
            }
            uint4 o;
            o.x = packh2(v[0], v[1]);
            o.y = packh2(v[2], v[3]);
            o.z = packh2(v[4], v[5]);
            o.w = packh2(v[6], v[7]);
            lsd[(ic * 6 + r) * 13 + j] = o;
        }
    }
    __syncthreads();

    const int lane = tid & 63;
    const int oc   = ocl * 8 + (tid >> 6);      // wave-uniform
    const int wl   = lane & 15;
    const int hr   = lane >> 4;
    const int h    = h0 + hr;
    const char* ldsb = (const char*)lsd;
    const int vb   = hr * ROWB + 12 * wl;       // per-lane byte offset
    const uint4* tb = tbl + oc * NROW;
    const uint32_t* rb = rmx + oc * NROW;

    uint32_t a0 = NEGH2, a1 = NEGH2, a2 = NEGH2;

    for (int c = 0; c < NROW / 2; ++c) {
        uint4 e0 = tb[2 * c], e1 = tb[2 * c + 1];   // uniform s_load
        uint32_t kn = (c < NROW / 2 - 1) ? rb[2 * c + 2] : 0u;

        u4a4 d = *(const u4a4*)(ldsb + e0.w + vb);
        u4a4 D = *(const u4a4*)(ldsb + e1.w + vb);

        uint32_t p01 = __builtin_amdgcn_alignbit(d.y, d.x, 16);
        uint32_t p12 = __builtin_amdgcn_alignbit(d.z, d.y, 16);
        uint32_t p23 = __builtin_amdgcn_alignbit(d.w, d.z, 16);
        a0 = pkmax(a0, pkmax(pkmax(pkmin_vs(d.x, e0.x), pkmin_vs(p01, e0.y)),
                             pkmin_vs(d.y, e0.z)));
        a1 = pkmax(a1, pkmax(pkmax(pkmin_vs(d.y, e0.x), pkmin_vs(p12, e0.y)),
                             pkmin_vs(d.z, e0.z)));
        a2 = pkmax(a2, pkmax(pkmax(pkmin_vs(d.z, e0.x), pkmin_vs(p23, e0.y)),
                             pkmin_vs(d.w, e0.z)));

        uint32_t q01 = __builtin_amdgcn_alignbit(D.y, D.x, 16);
        uint32_t q12 = __builtin_amdgcn_alignbit(D.z, D.y, 16);
        uint32_t q23 = __builtin_amdgcn_alignbit(D.w, D.z, 16);
        a0 = pkmax(a0, pkmax(pkmax(pkmin_vs(D.x, e1.x), pkmin_vs(q01, e1.y)),
                             pkmin_vs(D.y, e1.z)));
        a1 = pkmax(a1, pkmax(pkmax(pkmin_vs(D.y, e1.x), pkmin_vs(q12, e1.y)),
                             pkmin_vs(D.z, e1.z)));
        a2 = pkmax(a2, pkmax(pkmax(pkmin_vs(D.z, e1.x), pkmin_vs(q23, e1.y)),
                             pkmin_vs(D.w, e1.z)));

        if (c < NROW / 2 - 1) {
            // done iff min over all 6 px (both halves) >= next rowmax
            uint32_t mn = pkmin_vv(pkmin_vv(a0, a1), a2);
            mn = pkmin_vv(mn, __builtin_amdgcn_alignbit(mn, mn, 16));
            h2 a  = __builtin_bit_cast(h2, mn);
            h2 kv = __builtin_bit_cast(h2, kn);
            if (__all(a.x >= kv.x)) break;
        }
    }

    float* ob = out + (((size_t)(n * OCN + oc)) * HH + h) * WW + 6 * wl;
    h2 r0 = __builtin_bit_cast(h2, a0);
    h2 r1 = __builtin_bit_cast(h2, a1);
    h2 r2 = __builtin_bit_cast(h2, a2);
    *(float2*)(ob)     = make_float2((float)r0.x, (float)r0.y);
    *(float2*)(ob + 2) = make_float2((float)r1.x, (float)r1.y);
    *(float2*)(ob + 4) = make_float2((float)r2.x, (float)r2.y);
}

// ---------- f32 fallback if ws is too small ----------
#define NEGINF (-INFINITY)
__global__ __launch_bounds__(192, 8) void semiconv2d_f32(
    const float* __restrict__ x, const float* __restrict__ kk, float* __restrict__ out)
{
    const int tid = threadIdx.x;
    const int w  = tid % WW;
    const int hr = tid / WW;
    const int b   = blockIdx.x;
    const int ocb = b & 7;
    const int hp  = (b >> 3) % 48;
    const int n   = (b >> 3) / 48;
    const int h   = hp * 2 + hr;
    const int oc0 = ocb * 4;
    float a0[4], a1[4], a2[4];
#pragma unroll
    for (int i = 0; i < 4; ++i) { a0[i] = NEGINF; a1[i] = NEGINF; a2[i] = NEGINF; }
    const bool vm = (h > 0), vp = (h < HH - 1);
    const int hm  = vm ? h - 1 : h;
    const int hpl = vp ? h + 1 : h;
    const int cm  = (w > 0) ? -1 : 0;
    const int cp  = (w < WW - 1) ? 1 : 0;
    const float* rm = x + ((size_t)(n * CIN) * HH + hm)  * WW + w;
    const float* r1 = x + ((size_t)(n * CIN) * HH + h)   * WW + w;
    const float* rp = x + ((size_t)(n * CIN) * HH + hpl) * WW + w;
#pragma unroll 2
    for (int ic = 0; ic < CIN; ++ic) {
        float r00 = vm ? rm[cm] : NEGINF, r01 = vm ? rm[0] : NEGINF, r02 = vm ? rm[cp] : NEGINF;
        float r10 = r1[cm], r11 = r1[0], r12 = r1[cp];
        float r20 = vp ? rp[cm] : NEGINF, r21 = vp ? rp[0] : NEGINF, r22 = vp ? rp[cp] : NEGINF;
#pragma unroll
        for (int oc = 0; oc < 4; ++oc) {
            const float* kq = kk + (size_t)(((oc0 + oc) * CIN + ic)) * 9;
            a0[oc] = fmaxf(fmaxf(a0[oc], fminf(r00, kq[0])), fmaxf(fminf(r10, kq[3]), fminf(r20, kq[6])));
            a1[oc] = fmaxf(fmaxf(a1[oc], fminf(r01, kq[1])), fmaxf(fminf(r11, kq[4]), fminf(r21, kq[7])));
            a2[oc] = fmaxf(fmaxf(a2[oc], fminf(r02, kq[2])), fmaxf(fminf(r12, kq[5]), fminf(r22, kq[8])));
        }
        rm += HH * WW; r1 += HH * WW; rp += HH * WW;
    }
#pragma unroll
    for (int oc = 0; oc < 4; ++oc) {
        float v0 = (w > 0)      ? a0[oc] : NEGINF;
        float v2 = (w < WW - 1) ? a2[oc] : NEGINF;
        out[(((size_t)(n * OCN + oc0 + oc)) * HH + h) * WW + w] = fmaxf(fmaxf(v0, a1[oc]), v2);
    }
}

extern "C" void kernel_launch(void* const* d_in, const int* in_sizes, int n_in,
                              void* d_out, int out_size, void* d_ws, size_t ws_size,
                              hipStream_t stream) {
    const float* x  = (const float*)d_in[0];
    const float* kk = (const float*)d_in[1];
    float* out      = (float*)d_out;
    if (ws_size >= WS_NEED) {
        uint4*    tbl = (uint4*)d_ws;
        uint32_t* rmx = (uint32_t*)((char*)d_ws + TBL_BYTES);
        setup_tab<<<dim3(OCN), dim3(96), 0, stream>>>(kk, tbl, rmx);
        semiconv_x<<<dim3(4 * 24 * 8), dim3(512), 0, stream>>>(
            x, tbl, rmx, out);
    } else {
        semiconv2d_f32<<<dim3(8 * 48 * 8), dim3(192), 0, stream>>>(x, kk, out);
    }
}

// Round 10
// 87.126 us; speedup vs baseline: 1.1529x; 1.1529x over previous
//
#include <hip/hip_runtime.h>
#include <math.h>
#include <stdint.h>

// SemiConv2d tropical conv: out = max_{ic,kh,kw} min(x_pad, K). f16-packed.
// R22: R20 staging (xq pack + uint4 LDS stage) + CHUNKED EXIT (8 rows
// per check). R21 post-mortem: f32-direct staging cost +14us (8 scalar
// loads/unit vs 1 coalesced uint4) -> reverted. But R21 finally exposed
// main-kernel counters: VALUBusy 27%, HBM 11%, conflicts 7%, occupancy
// 48% -> NOTHING saturated = stall-bound. The never-ablated feature
// since R13: per-iteration early-exit branch. It forbids the compiler
// from hoisting loads across the break -> serial s_load->ds_read->VALU->
// branch ~330cy/iter, matching VALUBusy 27% and the conserved 4-5x gap
// over VALU/LDS floors (~6us each w/ exit). R22: 12 chunks x 8 rows;
// inner 4 pair-iters unrolled branch-free (8 ds_reads + 64B s_loads all
// in flight), ONE exit check per chunk. Keeps ~45% work saving (+~4 rows
// avg), cuts serialization 47->12. Exit exactness unchanged (per-oc
// rowmax-sorted, threshold = first row of next chunk) -> absmax 0.015625.
// Predict: main 42 -> 16-20 (VALUBusy -> ~50%), total 100.4 -> 75-80.
// PRE-COMMIT: if >=85, exit-serialization theory dead too; remaining =
// fill(44, HBM roofline) + setup + scan at empirical floor -> declare
// ROOFLINE next round.

#define HH 96
#define WW 96
#define CIN 32
#define OCN 32
#define XQ_ROWS 98
#define ROWB 208                                // 104 f16: w=-1..102, 16B units
#define ROWU4 13                                // 16B units per row
#define SLICEB (XQ_ROWS * ROWB)                 // 20384 B per (n,ic) slice
#define XQ_BYTES ((size_t)256 * SLICEB)         // 5,218,304 B
#define XQP_TOTAL (256 * XQ_ROWS * ROWU4)       // 326,144 pack threads
#define XQPB (XQP_TOTAL / 256)                  // 1274 pack blocks
#define NROW 96                                 // sorted row-entries per oc
#define TBL_BYTES ((size_t)OCN * NROW * 16)
#define RMX_BYTES ((size_t)OCN * NROW * 4)
#define WS_NEED (XQ_BYTES + TBL_BYTES + RMX_BYTES)
#define NEGH2 0xFC00FC00u
#define LDSU 2496                               // 32 ic * 6 rows * 13 units

typedef _Float16 h2 __attribute__((ext_vector_type(2)));
typedef uint32_t u4a4 __attribute__((ext_vector_type(4), aligned(4)));

__device__ __forceinline__ uint32_t pkmin_vs(uint32_t x, uint32_t k) {
    uint32_t d;
    asm("v_pk_min_f16 %0, %1, %2" : "=v"(d) : "v"(x), "s"(k));
    return d;
}
__device__ __forceinline__ uint32_t pkmin_vv(uint32_t a, uint32_t b) {
    uint32_t d;
    asm("v_pk_min_f16 %0, %1, %2" : "=v"(d) : "v"(a), "v"(b));
    return d;
}
__device__ __forceinline__ uint32_t pkmax(uint32_t a, uint32_t b) {
    uint32_t d;
    asm("v_pk_max_f16 %0, %1, %2" : "=v"(d) : "v"(a), "v"(b));
    return d;
}
__device__ __forceinline__ uint32_t packh2(float lo, float hi) {
    h2 p = {(_Float16)lo, (_Float16)hi};
    return __builtin_bit_cast(uint32_t, p);
}

// Fused setup (identical to R20).
// Blocks [0, XQPB): pack x -> xq. Row (s, hp): 104 f16, byte(w)=2(w+1),
//   w=-1..102, value = x[s][hp-1][w] or -inf. Thread u: 16B unit =
//   px w = 8u-1 .. 8u+6.
// Blocks [XQPB, XQPB+32): per-oc row table sorted by rowmax desc.
//   entry uint4 = {k0dup, k1dup, k2dup, LOCAL byte off (ic*6+dh)*208}
//   rmx[rank]  = rowmax dup (exit threshold bounds all remaining k).
__global__ __launch_bounds__(256) void setup_all(const float* __restrict__ x,
                                                 const float* __restrict__ kk,
                                                 uint4* __restrict__ xq,
                                                 uint4* __restrict__ tbl,
                                                 uint32_t* __restrict__ rmx) {
    __shared__ float rs[NROW];
    const int bb = blockIdx.x;
    if (bb < XQPB) {
        int idx = bb * 256 + threadIdx.x;       // over 256*98*13
        int u  = idx % ROWU4;                   // 16B unit in row
        int t  = idx / ROWU4;
        int hp = t % XQ_ROWS;
        int s  = t / XQ_ROWS;
        int h  = hp - 1;
        bool hv = (h >= 0) && (h < HH);
        const float* row = x + ((size_t)s * HH + (hv ? h : 0)) * WW;
        float v[8];
#pragma unroll
        for (int q = 0; q < 8; ++q) {
            int w = 8 * u - 1 + q;
            v[q] = (hv && w >= 0 && w < WW) ? row[w] : -INFINITY;
        }
        uint4 o;
        o.x = packh2(v[0], v[1]);
        o.y = packh2(v[2], v[3]);
        o.z = packh2(v[4], v[5]);
        o.w = packh2(v[6], v[7]);
        xq[idx] = o;
        return;
    }
    // ---- table path ----
    const int oc = bb - XQPB;
    const int t  = threadIdx.x;
    if (t >= NROW) return;
    const int ic = t / 3, dh = t - 3 * ic;
    const float* kp = kk + ((size_t)(oc * CIN + ic) * 3 + dh) * 3;
    float k0 = kp[0], k1 = kp[1], k2 = kp[2];
    float rm = fmaxf(fmaxf(k0, k1), k2);
    rs[t] = rm;
    __syncthreads();
    int rank = 0;
    for (int s = 0; s < NROW; ++s) {
        float v = rs[s];
        rank += (v > rm) || (v == rm && s < t);
    }
    uint32_t off = (uint32_t)(ic * 6 + dh) * ROWB;  // LOCAL offset in LDS tile
    tbl[oc * NROW + rank] = make_uint4(packh2(k0, k0), packh2(k1, k1),
                                       packh2(k2, k2), off);
    rmx[oc * NROW + rank] = packh2(rm, rm);
}

// Block = (n, 4 output h-rows, 8 ocs), 512 threads = 8 waves.
// Stage 6 xq rows (hp = h0..h0+5) x 32 ic into LDS (39,936 B), barrier,
// then each wave (one oc) scans sorted rows from LDS. Lane = 6 px:
// wl 0..15 (w0 = 6*wl), hr 0..3 (h = h0+hr). Per row one 16B window at
// e.w + hr*208 + 12*wl gives d0..d3; pair q: kw0=d_q,
// kw1=align(d_{q+1},d_q), kw2=d_{q+1}. Exit once per 8-row chunk.
__global__ __launch_bounds__(512, 4) void semiconv_ck(const char* __restrict__ xqb,
                                                      const uint4* __restrict__ tbl,
                                                      const uint32_t* __restrict__ rmx,
                                                      float* __restrict__ out) {
    __shared__ uint4 lsd[LDSU];
    const int tid = threadIdx.x;
    const int b   = blockIdx.x;
    const int ocl = b & 3;
    const int t   = b >> 2;
    const int ht  = t % 24;
    const int n   = t / 24;
    const int h0  = ht * 4;

    // ---- stage 6 rows x 32 ic (2496 x 16B) from packed xq ----
    const uint4* xg = (const uint4*)(xqb + (size_t)n * CIN * SLICEB);
#pragma unroll
    for (int i = 0; i < 5; ++i) {
        int u = tid + 512 * i;
        if (u < LDSU) {
            int ic = u / 78;                    // 6*13 units per ic
            int rr = u - ic * 78;
            int r  = rr / 13;
            int j  = rr - r * 13;
            lsd[(ic * 6 + r) * 13 + j] = xg[(ic * 98 + h0 + r) * 13 + j];
        }
    }
    __syncthreads();

    const int lane = tid & 63;
    const int oc   = ocl * 8 + (tid >> 6);      // wave-uniform
    const int wl   = lane & 15;
    const int hr   = lane >> 4;
    const int h    = h0 + hr;
    const char* ldsb = (const char*)lsd;
    const int vb   = hr * ROWB + 12 * wl;       // per-lane byte offset
    const uint4* tb = tbl + oc * NROW;
    const uint32_t* rb = rmx + oc * NROW;

    uint32_t a0 = NEGH2, a1 = NEGH2, a2 = NEGH2;

    for (int cc = 0; cc < 12; ++cc) {           // 12 chunks x 8 rows
#pragma unroll
        for (int i = 0; i < 4; ++i) {           // 4 row-pairs, branch-free
            const int c = 4 * cc + i;
            uint4 e0 = tb[2 * c], e1 = tb[2 * c + 1];   // uniform s_load

            u4a4 d = *(const u4a4*)(ldsb + e0.w + vb);
            u4a4 D = *(const u4a4*)(ldsb + e1.w + vb);

            uint32_t p01 = __builtin_amdgcn_alignbit(d.y, d.x, 16);
            uint32_t p12 = __builtin_amdgcn_alignbit(d.z, d.y, 16);
            uint32_t p23 = __builtin_amdgcn_alignbit(d.w, d.z, 16);
            a0 = pkmax(a0, pkmax(pkmax(pkmin_vs(d.x, e0.x), pkmin_vs(p01, e0.y)),
                                 pkmin_vs(d.y, e0.z)));
            a1 = pkmax(a1, pkmax(pkmax(pkmin_vs(d.y, e0.x), pkmin_vs(p12, e0.y)),
                                 pkmin_vs(d.z, e0.z)));
            a2 = pkmax(a2, pkmax(pkmax(pkmin_vs(d.z, e0.x), pkmin_vs(p23, e0.y)),
                                 pkmin_vs(d.w, e0.z)));

            uint32_t q01 = __builtin_amdgcn_alignbit(D.y, D.x, 16);
            uint32_t q12 = __builtin_amdgcn_alignbit(D.z, D.y, 16);
            uint32_t q23 = __builtin_amdgcn_alignbit(D.w, D.z, 16);
            a0 = pkmax(a0, pkmax(pkmax(pkmin_vs(D.x, e1.x), pkmin_vs(q01, e1.y)),
                                 pkmin_vs(D.y, e1.z)));
            a1 = pkmax(a1, pkmax(pkmax(pkmin_vs(D.y, e1.x), pkmin_vs(q12, e1.y)),
                                 pkmin_vs(D.z, e1.z)));
            a2 = pkmax(a2, pkmax(pkmax(pkmin_vs(D.z, e1.x), pkmin_vs(q23, e1.y)),
                                 pkmin_vs(D.w, e1.z)));
        }

        if (cc < 11) {
            // done iff min over all 6 px (both halves) >= max of remaining
            // rows = rowmax of first row of next chunk (sorted desc).
            uint32_t kn = rb[8 * (cc + 1)];
            uint32_t mn = pkmin_vv(pkmin_vv(a0, a1), a2);
            mn = pkmin_vv(mn, __builtin_amdgcn_alignbit(mn, mn, 16));
            h2 a  = __builtin_bit_cast(h2, mn);
            h2 kv = __builtin_bit_cast(h2, kn);
            if (__all(a.x >= kv.x)) break;
        }
    }

    float* ob = out + (((size_t)(n * OCN + oc)) * HH + h) * WW + 6 * wl;
    h2 r0 = __builtin_bit_cast(h2, a0);
    h2 r1 = __builtin_bit_cast(h2, a1);
    h2 r2 = __builtin_bit_cast(h2, a2);
    *(float2*)(ob)     = make_float2((float)r0.x, (float)r0.y);
    *(float2*)(ob + 2) = make_float2((float)r1.x, (float)r1.y);
    *(float2*)(ob + 4) = make_float2((float)r2.x, (float)r2.y);
}

// ---------- f32 fallback if ws is too small ----------
#define NEGINF (-INFINITY)
__global__ __launch_bounds__(192, 8) void semiconv2d_f32(
    const float* __restrict__ x, const float* __restrict__ kk, float* __restrict__ out)
{
    const int tid = threadIdx.x;
    const int w  = tid % WW;
    const int hr = tid / WW;
    const int b   = blockIdx.x;
    const int ocb = b & 7;
    const int hp  = (b >> 3) % 48;
    const int n   = (b >> 3) / 48;
    const int h   = hp * 2 + hr;
    const int oc0 = ocb * 4;
    float a0[4], a1[4], a2[4];
#pragma unroll
    for (int i = 0; i < 4; ++i) { a0[i] = NEGINF; a1[i] = NEGINF; a2[i] = NEGINF; }
    const bool vm = (h > 0), vp = (h < HH - 1);
    const int hm  = vm ? h - 1 : h;
    const int hpl = vp ? h + 1 : h;
    const int cm  = (w > 0) ? -1 : 0;
    const int cp  = (w < WW - 1) ? 1 : 0;
    const float* rm = x + ((size_t)(n * CIN) * HH + hm)  * WW + w;
    const float* r1 = x + ((size_t)(n * CIN) * HH + h)   * WW + w;
    const float* rp = x + ((size_t)(n * CIN) * HH + hpl) * WW + w;
#pragma unroll 2
    for (int ic = 0; ic < CIN; ++ic) {
        float r00 = vm ? rm[cm] : NEGINF, r01 = vm ? rm[0] : NEGINF, r02 = vm ? rm[cp] : NEGINF;
        float r10 = r1[cm], r11 = r1[0], r12 = r1[cp];
        float r20 = vp ? rp[cm] : NEGINF, r21 = vp ? rp[0] : NEGINF, r22 = vp ? rp[cp] : NEGINF;
#pragma unroll
        for (int oc = 0; oc < 4; ++oc) {
            const float* kq = kk + (size_t)(((oc0 + oc) * CIN + ic)) * 9;
            a0[oc] = fmaxf(fmaxf(a0[oc], fminf(r00, kq[0])), fmaxf(fminf(r10, kq[3]), fminf(r20, kq[6])));
            a1[oc] = fmaxf(fmaxf(a1[oc], fminf(r01, kq[1])), fmaxf(fminf(r11, kq[4]), fminf(r21, kq[7])));
            a2[oc] = fmaxf(fmaxf(a2[oc], fminf(r02, kq[2])), fmaxf(fminf(r12, kq[5]), fminf(r22, kq[8])));
        }
        rm += HH * WW; r1 += HH * WW; rp += HH * WW;
    }
#pragma unroll
    for (int oc = 0; oc < 4; ++oc) {
        float v0 = (w > 0)      ? a0[oc] : NEGINF;
        float v2 = (w < WW - 1) ? a2[oc] : NEGINF;
        out[(((size_t)(n * OCN + oc0 + oc)) * HH + h) * WW + w] = fmaxf(fmaxf(v0, a1[oc]), v2);
    }
}

extern "C" void kernel_launch(void* const* d_in, const int* in_sizes, int n_in,
                              void* d_out, int out_size, void* d_ws, size_t ws_size,
                              hipStream_t stream) {
    const float* x  = (const float*)d_in[0];
    const float* kk = (const float*)d_in[1];
    float* out      = (float*)d_out;
    if (ws_size >= WS_NEED) {
        uint4*    xq  = (uint4*)d_ws;
        uint4*    tbl = (uint4*)((char*)d_ws + XQ_BYTES);
        uint32_t* rmx = (uint32_t*)((char*)d_ws + XQ_BYTES + TBL_BYTES);
        setup_all<<<dim3(XQPB + OCN), dim3(256), 0, stream>>>(x, kk, xq, tbl, rmx);
        semiconv_ck<<<dim3(4 * 24 * 8), dim3(512), 0, stream>>>(
            (const char*)xq, tbl, rmx, out);
    } else {
        semiconv2d_f32<<<dim3(8 * 48 * 8), dim3(192), 0, stream>>>(x, kk, out);
    }
}